// Round 1
// baseline (469.014 us; speedup 1.0000x reference)
//
#include <hip/hip_runtime.h>

#define S_LEN 4096   // H*W
#define C_CH  256
#define D_CH  128
// softmax scale folded into exp2: lambda = (1/sqrt(256)) * log2(e)
#define LAMBDA 0.09016844005555896f

typedef __attribute__((ext_vector_type(8))) short short8;   // 8 x bf16 (4 VGPR)
typedef __attribute__((ext_vector_type(4))) float f32x4;

static __device__ __forceinline__ unsigned short f2bf(float x) {
    union { float f; unsigned u; } v; v.f = x;
    unsigned r = v.u + 0x7FFFu + ((v.u >> 16) & 1u);   // RNE
    return (unsigned short)(r >> 16);
}

// ---------- kernel 1: x f32 -> xb bf16, layout [n][c][s] (V operand) ----------
__global__ void nlm_conv_kernel(const float* __restrict__ x, unsigned short* __restrict__ xb) {
    size_t base = ((size_t)blockIdx.x * 256 + threadIdx.x) * 4;
    float4 v = *reinterpret_cast<const float4*>(x + base);
    ushort4 b; b.x = f2bf(v.x); b.y = f2bf(v.y); b.z = f2bf(v.z); b.w = f2bf(v.w);
    *reinterpret_cast<ushort4*>(xb + base) = b;
}

// ---------- kernel 2: theta_w/phi_w f32 -> bf16, wb = [2][128][256] ----------
__global__ void nlm_wconv_kernel(const float* __restrict__ tw, const float* __restrict__ pw,
                                 unsigned short* __restrict__ wb) {
    int base = (blockIdx.x * 256 + threadIdx.x) * 4;
    const float* src = (base < 32768) ? (tw + base) : (pw + base - 32768);
    float4 v = *reinterpret_cast<const float4*>(src);
    ushort4 b; b.x = f2bf(v.x); b.y = f2bf(v.y); b.z = f2bf(v.z); b.w = f2bf(v.w);
    *reinterpret_cast<ushort4*>(wb + base) = b;
}

// ---------- kernel 3: projections Q[n][s][128], K[n][t][128] (bf16) ----------
// Q[s][d] = sum_c x[c][s] * theta_w[d][c] + theta_b[d]   (same for K with phi)
// MFMA: D[s][d] = A[s][c] * B[c][d]; A read strided from f32 x, B from wb (16B frags).
__launch_bounds__(256, 1)
__global__ void nlm_proj_kernel(const float* __restrict__ x,
                                const unsigned short* __restrict__ wb,
                                const float* __restrict__ tb, const float* __restrict__ pbias,
                                unsigned short* __restrict__ Qb, unsigned short* __restrict__ Kb) {
    const int n    = blockIdx.y;
    const int wave = threadIdx.x >> 6;
    const int lane = threadIdx.x & 63;
    const int sl   = lane & 15, g = lane >> 4;
    const int s0   = blockIdx.x * 64 + wave * 16;
    const float* xn = x + (size_t)n * C_CH * S_LEN;

    f32x4 acc[16];
    #pragma unroll
    for (int i = 0; i < 16; ++i) acc[i] = (f32x4){0.f, 0.f, 0.f, 0.f};

    #pragma unroll 1
    for (int cc = 0; cc < 8; ++cc) {
        short8 af;                                   // A[m=s][k=c]: lane m=sl, k=g*8+j
        #pragma unroll
        for (int j = 0; j < 8; ++j) {
            float v = xn[(size_t)(cc * 32 + g * 8 + j) * S_LEN + s0 + sl];
            af[j] = (short)f2bf(v);
        }
        #pragma unroll
        for (int t = 0; t < 16; ++t) {               // 0..7 theta tiles, 8..15 phi tiles
            const unsigned short* wp = wb + (size_t)(t >> 3) * (D_CH * C_CH)
                                          + (size_t)((t & 7) * 16 + sl) * C_CH + cc * 32 + g * 8;
            short8 bf = *reinterpret_cast<const short8*>(wp);
            acc[t] = __builtin_amdgcn_mfma_f32_16x16x32_bf16(af, bf, acc[t], 0, 0, 0);
        }
    }
    unsigned short* Qn = Qb + (size_t)n * S_LEN * D_CH;
    unsigned short* Kn = Kb + (size_t)n * S_LEN * D_CH;
    #pragma unroll
    for (int t = 0; t < 16; ++t) {
        const float bias = (t < 8 ? tb : pbias)[(t & 7) * 16 + sl];
        unsigned short* dst = (t < 8 ? Qn : Kn);
        #pragma unroll
        for (int r = 0; r < 4; ++r) {                // D row = g*4+r, col = sl
            dst[(size_t)(s0 + g * 4 + r) * D_CH + (t & 7) * 16 + sl] = f2bf(acc[t][r] + bias);
        }
    }
}

// ---------- kernel 4: flash attention, O^T = V^T * P^T ----------
// Block = 4 waves, 64 q-rows (16/wave), shared t-loop (BT=32) for L1 reuse of K/V frags.
__launch_bounds__(256, 1)
__global__ void nlm_attn_kernel(const unsigned short* __restrict__ Qb,
                                const unsigned short* __restrict__ Kb,
                                const unsigned short* __restrict__ xb,
                                float* __restrict__ out) {
    const int n    = blockIdx.y;
    const int wave = threadIdx.x >> 6;
    const int lane = threadIdx.x & 63;
    const int sl   = lane & 15, g = lane >> 4;
    const int s0   = blockIdx.x * 64 + wave * 16;

    __shared__ unsigned short Plds[4][16 * 40];      // per-wave P^T staging, pitch 40 (2-way banks)
    unsigned short* myP = &Plds[wave][0];

    const unsigned short* Qn = Qb + (size_t)n * S_LEN * D_CH;
    const unsigned short* Kn = Kb + (size_t)n * S_LEN * D_CH;
    const unsigned short* xn = xb + (size_t)n * C_CH * S_LEN;

    short8 qf[4];                                    // B[k=d][n=s]: lane n=sl, k=g*8+j (+dc*32)
    #pragma unroll
    for (int dc = 0; dc < 4; ++dc)
        qf[dc] = *reinterpret_cast<const short8*>(Qn + (size_t)(s0 + sl) * D_CH + dc * 32 + g * 8);

    f32x4 oacc[16];                                  // O^T[i][s]: 256 i x 16 s per wave
    #pragma unroll
    for (int i = 0; i < 16; ++i) oacc[i] = (f32x4){0.f, 0.f, 0.f, 0.f};
    float m = -1e30f, lsum = 0.f;

    #pragma unroll 1
    for (int it = 0; it < 128; ++it) {
        const int t0 = it * 32;
        f32x4 sacc0 = {0.f, 0.f, 0.f, 0.f}, sacc1 = {0.f, 0.f, 0.f, 0.f};
        #pragma unroll
        for (int dc = 0; dc < 4; ++dc) {             // S^T = K_tile * Q^T  (swapped operands)
            short8 kf0 = *reinterpret_cast<const short8*>(Kn + (size_t)(t0 + sl) * D_CH + dc * 32 + g * 8);
            short8 kf1 = *reinterpret_cast<const short8*>(Kn + (size_t)(t0 + 16 + sl) * D_CH + dc * 32 + g * 8);
            sacc0 = __builtin_amdgcn_mfma_f32_16x16x32_bf16(kf0, qf[dc], sacc0, 0, 0, 0);
            sacc1 = __builtin_amdgcn_mfma_f32_16x16x32_bf16(kf1, qf[dc], sacc1, 0, 0, 0);
        }
        // lane holds S[s=sl][t = t0 + tt*16 + g*4 + r]
        float p[8];
        p[0] = sacc0[0]; p[1] = sacc0[1]; p[2] = sacc0[2]; p[3] = sacc0[3];
        p[4] = sacc1[0]; p[5] = sacc1[1]; p[6] = sacc1[2]; p[7] = sacc1[3];
        float pmax = fmaxf(fmaxf(fmaxf(p[0], p[1]), fmaxf(p[2], p[3])),
                           fmaxf(fmaxf(p[4], p[5]), fmaxf(p[6], p[7])));
        pmax = fmaxf(pmax, __shfl_xor(pmax, 16));
        pmax = fmaxf(pmax, __shfl_xor(pmax, 32));
        const float mnew = fmaxf(m, pmax);
        float rs = 0.f;
        #pragma unroll
        for (int j = 0; j < 8; ++j) {
            p[j] = __builtin_amdgcn_exp2f((p[j] - mnew) * LAMBDA);
            rs += p[j];
        }
        rs += __shfl_xor(rs, 16);
        rs += __shfl_xor(rs, 32);
        if (!__all(mnew == m)) {                     // wave-uniform skip-rescale (T13-lite)
            const float alpha = __builtin_amdgcn_exp2f((m - mnew) * LAMBDA);
            lsum *= alpha;
            #pragma unroll
            for (int i = 0; i < 16; ++i) {
                oacc[i][0] *= alpha; oacc[i][1] *= alpha;
                oacc[i][2] *= alpha; oacc[i][3] *= alpha;
            }
            m = mnew;
        }
        lsum += rs;
        // P^T -> LDS (bf16), then reload as B-fragment: lane n=sl needs P[sl][g*8+j]
        ushort4 w0, w1;
        w0.x = f2bf(p[0]); w0.y = f2bf(p[1]); w0.z = f2bf(p[2]); w0.w = f2bf(p[3]);
        w1.x = f2bf(p[4]); w1.y = f2bf(p[5]); w1.z = f2bf(p[6]); w1.w = f2bf(p[7]);
        *reinterpret_cast<ushort4*>(myP + sl * 40 + g * 4)      = w0;   // t_local = g*4+r
        *reinterpret_cast<ushort4*>(myP + sl * 40 + 16 + g * 4) = w1;   // t_local = 16+g*4+r
        short8 pf = *reinterpret_cast<const short8*>(myP + sl * 40 + g * 8);
        // O^T += V^T * P^T : A[m=i][k=t] = xb[i][t0+k], 16 i-tiles
        #pragma unroll
        for (int i2 = 0; i2 < 16; ++i2) {
            short8 vf = *reinterpret_cast<const short8*>(xn + (size_t)(i2 * 16 + sl) * S_LEN + t0 + g * 8);
            oacc[i2] = __builtin_amdgcn_mfma_f32_16x16x32_bf16(vf, pf, oacc[i2], 0, 0, 0);
        }
        __syncthreads();                             // keep waves' t-windows aligned for L1 reuse
    }
    const float inv = 1.f / lsum;                    // row sum (uniform across g for this sl)
    float* on = out + (size_t)n * C_CH * S_LEN;
    #pragma unroll
    for (int i2 = 0; i2 < 16; ++i2) {
        #pragma unroll
        for (int r = 0; r < 4; ++r) {
            on[(size_t)(i2 * 16 + g * 4 + r) * S_LEN + s0 + sl] = oacc[i2][r] * inv;
        }
    }
}

extern "C" void kernel_launch(void* const* d_in, const int* in_sizes, int n_in,
                              void* d_out, int out_size, void* d_ws, size_t ws_size,
                              hipStream_t stream) {
    const float* x  = (const float*)d_in[0];
    const float* tw = (const float*)d_in[1];
    const float* tb = (const float*)d_in[2];
    const float* pw = (const float*)d_in[3];
    const float* pb = (const float*)d_in[4];
    float* out = (float*)d_out;

    char* ws = (char*)d_ws;
    unsigned short* xb = (unsigned short*)(ws);               //  8,388,608 B
    unsigned short* Qb = (unsigned short*)(ws + 8388608);     //  4,194,304 B
    unsigned short* Kb = (unsigned short*)(ws + 12582912);    //  4,194,304 B
    unsigned short* wb = (unsigned short*)(ws + 16777216);    //    131,072 B

    nlm_conv_kernel<<<4096, 256, 0, stream>>>(x, xb);
    nlm_wconv_kernel<<<64, 256, 0, stream>>>(tw, pw, wb);
    nlm_proj_kernel<<<dim3(64, 4), 256, 0, stream>>>(x, wb, tb, pb, Qb, Kb);
    nlm_attn_kernel<<<dim3(64, 4), 256, 0, stream>>>(Qb, Kb, xb, out);
}

// Round 2
// 231.520 us; speedup vs baseline: 2.0258x; 2.0258x over previous
//
#include <hip/hip_runtime.h>

#define S_LEN 4096   // H*W
#define C_CH  256
#define D_CH  128
#define NT    128    // t-tiles of 32
// softmax scale folded into exp2: lambda = (1/sqrt(256)) * log2(e)
#define LAMBDA 0.09016844005555896f

typedef __attribute__((ext_vector_type(8))) short short8;   // 8 x bf16 (4 VGPR)
typedef __attribute__((ext_vector_type(4))) float f32x4;

static __device__ __forceinline__ unsigned short f2bf(float x) {
    union { float f; unsigned u; } v; v.f = x;
    unsigned r = v.u + 0x7FFFu + ((v.u >> 16) & 1u);   // RNE
    return (unsigned short)(r >> 16);
}

static __device__ __forceinline__ void gload_lds16(const void* g, void* l) {
    __builtin_amdgcn_global_load_lds(
        (const __attribute__((address_space(1))) void*)g,
        (__attribute__((address_space(3))) void*)l, 16, 0, 0);
}

// ---------- kernel 1: x f32 -> xb bf16, layout [n][c][s] (V operand) ----------
__global__ void nlm_conv_kernel(const float* __restrict__ x, unsigned short* __restrict__ xb) {
    size_t base = ((size_t)blockIdx.x * 256 + threadIdx.x) * 4;
    float4 v = *reinterpret_cast<const float4*>(x + base);
    ushort4 b; b.x = f2bf(v.x); b.y = f2bf(v.y); b.z = f2bf(v.z); b.w = f2bf(v.w);
    *reinterpret_cast<ushort4*>(xb + base) = b;
}

// ---------- kernel 2: theta_w/phi_w f32 -> bf16, wb = [2][128][256] ----------
__global__ void nlm_wconv_kernel(const float* __restrict__ tw, const float* __restrict__ pw,
                                 unsigned short* __restrict__ wb) {
    int base = (blockIdx.x * 256 + threadIdx.x) * 4;
    const float* src = (base < 32768) ? (tw + base) : (pw + base - 32768);
    float4 v = *reinterpret_cast<const float4*>(src);
    ushort4 b; b.x = f2bf(v.x); b.y = f2bf(v.y); b.z = f2bf(v.z); b.w = f2bf(v.w);
    *reinterpret_cast<ushort4*>(wb + base) = b;
}

// ---------- kernel 3: projections Q[n][s][128], K[n][t][128] (bf16) ----------
__launch_bounds__(256, 1)
__global__ void nlm_proj_kernel(const float* __restrict__ x,
                                const unsigned short* __restrict__ wb,
                                const float* __restrict__ tb, const float* __restrict__ pbias,
                                unsigned short* __restrict__ Qb, unsigned short* __restrict__ Kb) {
    const int n    = blockIdx.y;
    const int wave = threadIdx.x >> 6;
    const int lane = threadIdx.x & 63;
    const int sl   = lane & 15, g = lane >> 4;
    const int s0   = blockIdx.x * 64 + wave * 16;
    const float* xn = x + (size_t)n * C_CH * S_LEN;

    f32x4 acc[16];
    #pragma unroll
    for (int i = 0; i < 16; ++i) acc[i] = (f32x4){0.f, 0.f, 0.f, 0.f};

    #pragma unroll 1
    for (int cc = 0; cc < 8; ++cc) {
        short8 af;                                   // A[m=s][k=c]: lane m=sl, k=g*8+j
        #pragma unroll
        for (int j = 0; j < 8; ++j) {
            float v = xn[(size_t)(cc * 32 + g * 8 + j) * S_LEN + s0 + sl];
            af[j] = (short)f2bf(v);
        }
        #pragma unroll
        for (int t = 0; t < 16; ++t) {               // 0..7 theta tiles, 8..15 phi tiles
            const unsigned short* wp = wb + (size_t)(t >> 3) * (D_CH * C_CH)
                                          + (size_t)((t & 7) * 16 + sl) * C_CH + cc * 32 + g * 8;
            short8 bf = *reinterpret_cast<const short8*>(wp);
            acc[t] = __builtin_amdgcn_mfma_f32_16x16x32_bf16(af, bf, acc[t], 0, 0, 0);
        }
    }
    unsigned short* Qn = Qb + (size_t)n * S_LEN * D_CH;
    unsigned short* Kn = Kb + (size_t)n * S_LEN * D_CH;
    #pragma unroll
    for (int t = 0; t < 16; ++t) {
        const float bias = (t < 8 ? tb : pbias)[(t & 7) * 16 + sl];
        unsigned short* dst = (t < 8 ? Qn : Kn);
        #pragma unroll
        for (int r = 0; r < 4; ++r) {                // D row = g*4+r, col = sl
            dst[(size_t)(s0 + g * 4 + r) * D_CH + (t & 7) * 16 + sl] = f2bf(acc[t][r] + bias);
        }
    }
}

// ---------- kernel 4: flash attention, O^T = V^T * P^T ----------
// 256 blocks (XCD-swizzled: one half-batch per XCD), 4 waves, 64 q-rows/block.
// K/V tiles double-buffered in LDS via global_load_lds; K tile XOR-swizzled.
__launch_bounds__(256, 1)
__global__ void nlm_attn_kernel(const unsigned short* __restrict__ Qb,
                                const unsigned short* __restrict__ Kb,
                                const unsigned short* __restrict__ xb,
                                float* __restrict__ out) {
    // XCD swizzle: 256 blocks, 8 XCDs, 32 consecutive work-items per XCD.
    const int sid  = blockIdx.x;
    const int newb = (sid & 7) * 32 + (sid >> 3);
    const int n    = newb >> 6;
    const int bx   = newb & 63;
    const int wave = threadIdx.x >> 6;
    const int lane = threadIdx.x & 63;
    const int sl   = lane & 15, g = lane >> 4;
    const int s0   = bx * 64 + wave * 16;

    __shared__ unsigned short Klds[2][32 * 128];     // [t-local][d], chunk-XOR swizzled
    __shared__ unsigned short Vlds[2][256 * 32];     // [c][t-local]
    __shared__ unsigned short Plds[4][16 * 40];      // per-wave P^T staging, pitch 40

    const unsigned short* Qn = Qb + (size_t)n * S_LEN * D_CH;
    const unsigned short* Kn = Kb + (size_t)n * S_LEN * D_CH;
    const unsigned short* xn = xb + (size_t)n * C_CH * S_LEN;
    unsigned short* myP = &Plds[wave][0];

    short8 qf[4];                                    // B[k=d][n=s]: lane n=sl, k=g*8+j (+dc*32)
    #pragma unroll
    for (int dc = 0; dc < 4; ++dc)
        qf[dc] = *reinterpret_cast<const short8*>(Qn + (size_t)(s0 + sl) * D_CH + dc * 32 + g * 8);

    f32x4 oacc[16];                                  // O^T[i][s]: 256 i x 16 s per wave
    #pragma unroll
    for (int i = 0; i < 16; ++i) oacc[i] = (f32x4){0.f, 0.f, 0.f, 0.f};
    float m = -1e30f, lsum = 0.f;

    // ---- cooperative stage of tile `it` into buffer `buf` ----
    auto stage = [&](int it, int buf) {
        const int t0 = it * 32;
        // K tile: 32 rows x 256B; wave stages rows wave*8..wave*8+7 (2 insts).
        // LDS[r][q] = Global[t0+r][q ^ (r&7)]  (16B chunks q=0..15)
        #pragma unroll
        for (int i = 0; i < 2; ++i) {
            const int rl = wave * 8 + i * 4 + (lane >> 4);
            const int ch = (lane & 15) ^ (rl & 7);
            const unsigned short* src = Kn + (size_t)(t0 + rl) * D_CH + ch * 8;
            gload_lds16(src, &Klds[buf][(wave * 8 + i * 4) * 128]);
        }
        // V tile: 256 rows x 64B; wave stages rows wave*64..wave*64+63 (4 insts).
        #pragma unroll
        for (int i = 0; i < 4; ++i) {
            const int row = wave * 64 + i * 16 + (lane >> 2);
            const unsigned short* src = xn + (size_t)row * S_LEN + t0 + (lane & 3) * 8;
            gload_lds16(src, &Vlds[buf][(wave * 64 + i * 16) * 32]);
        }
    };

    stage(0, 0);
    __syncthreads();                                 // implicit vmcnt(0) drain
    int cur = 0;

    #pragma unroll 1
    for (int it = 0; it < NT; ++it) {
        if (it + 1 < NT) stage(it + 1, cur ^ 1);     // prefetch overlaps this iter's compute

        const unsigned short* Kl = &Klds[cur][0];
        const unsigned short* Vl = &Vlds[cur][0];

        f32x4 sacc0 = {0.f, 0.f, 0.f, 0.f}, sacc1 = {0.f, 0.f, 0.f, 0.f};
        #pragma unroll
        for (int dc = 0; dc < 4; ++dc) {             // S^T = K_tile * Q^T (swapped operands)
            const int ch = (dc * 4 + g) ^ (sl & 7);  // un-swizzle
            short8 kf0 = *reinterpret_cast<const short8*>(Kl + sl * 128 + ch * 8);
            short8 kf1 = *reinterpret_cast<const short8*>(Kl + (16 + sl) * 128 + ch * 8);
            sacc0 = __builtin_amdgcn_mfma_f32_16x16x32_bf16(kf0, qf[dc], sacc0, 0, 0, 0);
            sacc1 = __builtin_amdgcn_mfma_f32_16x16x32_bf16(kf1, qf[dc], sacc1, 0, 0, 0);
        }
        // lane holds S[s=sl][t = t0 + tt*16 + g*4 + r]
        float p[8];
        p[0] = sacc0[0]; p[1] = sacc0[1]; p[2] = sacc0[2]; p[3] = sacc0[3];
        p[4] = sacc1[0]; p[5] = sacc1[1]; p[6] = sacc1[2]; p[7] = sacc1[3];
        float pmax = fmaxf(fmaxf(fmaxf(p[0], p[1]), fmaxf(p[2], p[3])),
                           fmaxf(fmaxf(p[4], p[5]), fmaxf(p[6], p[7])));
        pmax = fmaxf(pmax, __shfl_xor(pmax, 16));
        pmax = fmaxf(pmax, __shfl_xor(pmax, 32));
        const float mnew = fmaxf(m, pmax);
        float rs = 0.f;
        #pragma unroll
        for (int j = 0; j < 8; ++j) {
            p[j] = __builtin_amdgcn_exp2f((p[j] - mnew) * LAMBDA);
            rs += p[j];
        }
        rs += __shfl_xor(rs, 16);
        rs += __shfl_xor(rs, 32);
        if (!__all(mnew == m)) {                     // wave-uniform skip-rescale
            const float alpha = __builtin_amdgcn_exp2f((m - mnew) * LAMBDA);
            lsum *= alpha;
            #pragma unroll
            for (int i = 0; i < 16; ++i) {
                oacc[i][0] *= alpha; oacc[i][1] *= alpha;
                oacc[i][2] *= alpha; oacc[i][3] *= alpha;
            }
            m = mnew;
        }
        lsum += rs;
        // P^T -> LDS (bf16), reload as B-fragment: lane n=sl needs P[sl][g*8+j]
        ushort4 w0, w1;
        w0.x = f2bf(p[0]); w0.y = f2bf(p[1]); w0.z = f2bf(p[2]); w0.w = f2bf(p[3]);
        w1.x = f2bf(p[4]); w1.y = f2bf(p[5]); w1.z = f2bf(p[6]); w1.w = f2bf(p[7]);
        *reinterpret_cast<ushort4*>(myP + sl * 40 + g * 4)      = w0;
        *reinterpret_cast<ushort4*>(myP + sl * 40 + 16 + g * 4) = w1;
        short8 pf = *reinterpret_cast<const short8*>(myP + sl * 40 + g * 8);
        // O^T += V^T * P^T : A[m=i][k=t] = Vlds[i][k], 16 i-tiles
        #pragma unroll
        for (int i2 = 0; i2 < 16; ++i2) {
            short8 vf = *reinterpret_cast<const short8*>(Vl + (i2 * 16 + sl) * 32 + g * 8);
            oacc[i2] = __builtin_amdgcn_mfma_f32_16x16x32_bf16(vf, pf, oacc[i2], 0, 0, 0);
        }
        __syncthreads();                             // drains vmcnt -> next tile ready
        cur ^= 1;
    }
    const float inv = 1.f / lsum;
    float* on = out + (size_t)n * C_CH * S_LEN;
    #pragma unroll
    for (int i2 = 0; i2 < 16; ++i2) {
        #pragma unroll
        for (int r = 0; r < 4; ++r) {
            on[(size_t)(i2 * 16 + g * 4 + r) * S_LEN + s0 + sl] = oacc[i2][r] * inv;
        }
    }
}

extern "C" void kernel_launch(void* const* d_in, const int* in_sizes, int n_in,
                              void* d_out, int out_size, void* d_ws, size_t ws_size,
                              hipStream_t stream) {
    const float* x  = (const float*)d_in[0];
    const float* tw = (const float*)d_in[1];
    const float* tb = (const float*)d_in[2];
    const float* pw = (const float*)d_in[3];
    const float* pb = (const float*)d_in[4];
    float* out = (float*)d_out;

    char* ws = (char*)d_ws;
    unsigned short* xb = (unsigned short*)(ws);               //  8,388,608 B
    unsigned short* Qb = (unsigned short*)(ws + 8388608);     //  4,194,304 B
    unsigned short* Kb = (unsigned short*)(ws + 12582912);    //  4,194,304 B
    unsigned short* wb = (unsigned short*)(ws + 16777216);    //    131,072 B

    nlm_conv_kernel<<<4096, 256, 0, stream>>>(x, xb);
    nlm_wconv_kernel<<<64, 256, 0, stream>>>(tw, pw, wb);
    nlm_proj_kernel<<<dim3(64, 4), 256, 0, stream>>>(x, wb, tb, pb, Qb, Kb);
    nlm_attn_kernel<<<256, 256, 0, stream>>>(Qb, Kb, xb, out);
}

// Round 3
// 192.244 us; speedup vs baseline: 2.4397x; 1.2043x over previous
//
#include <hip/hip_runtime.h>

#define S_LEN 4096   // H*W
#define C_CH  256
#define D_CH  128
#define NT    128    // t-tiles of 32
// softmax scale folded into exp2: lambda = (1/sqrt(256)) * log2(e)
#define LAMBDA 0.09016844005555896f

typedef __attribute__((ext_vector_type(8))) short short8;   // 8 x bf16 (4 VGPR)
typedef __attribute__((ext_vector_type(4))) float f32x4;

static __device__ __forceinline__ unsigned short f2bf(float x) {
    union { float f; unsigned u; } v; v.f = x;
    unsigned r = v.u + 0x7FFFu + ((v.u >> 16) & 1u);   // RNE
    return (unsigned short)(r >> 16);
}

static __device__ __forceinline__ void gload_lds16(const void* g, void* l) {
    __builtin_amdgcn_global_load_lds(
        (const __attribute__((address_space(1))) void*)g,
        (__attribute__((address_space(3))) void*)l, 16, 0, 0);
}

// ---------- kernel 1: x f32 -> xb bf16, layout [n][c][s] (V operand) ----------
__global__ void nlm_conv_kernel(const float* __restrict__ x, unsigned short* __restrict__ xb) {
    size_t base = ((size_t)blockIdx.x * 256 + threadIdx.x) * 4;
    float4 v = *reinterpret_cast<const float4*>(x + base);
    ushort4 b; b.x = f2bf(v.x); b.y = f2bf(v.y); b.z = f2bf(v.z); b.w = f2bf(v.w);
    *reinterpret_cast<ushort4*>(xb + base) = b;
}

// ---------- kernel 2: theta_w/phi_w f32 -> bf16, wb = [2][128][256] ----------
__global__ void nlm_wconv_kernel(const float* __restrict__ tw, const float* __restrict__ pw,
                                 unsigned short* __restrict__ wb) {
    int base = (blockIdx.x * 256 + threadIdx.x) * 4;
    const float* src = (base < 32768) ? (tw + base) : (pw + base - 32768);
    float4 v = *reinterpret_cast<const float4*>(src);
    ushort4 b; b.x = f2bf(v.x); b.y = f2bf(v.y); b.z = f2bf(v.z); b.w = f2bf(v.w);
    *reinterpret_cast<ushort4*>(wb + base) = b;
}

// ---------- kernel 3: projections Q[n][s][128], K[n][t][128] (bf16) ----------
__launch_bounds__(256, 1)
__global__ void nlm_proj_kernel(const float* __restrict__ x,
                                const unsigned short* __restrict__ wb,
                                const float* __restrict__ tb, const float* __restrict__ pbias,
                                unsigned short* __restrict__ Qb, unsigned short* __restrict__ Kb) {
    const int n    = blockIdx.y;
    const int wave = threadIdx.x >> 6;
    const int lane = threadIdx.x & 63;
    const int sl   = lane & 15, g = lane >> 4;
    const int s0   = blockIdx.x * 64 + wave * 16;
    const float* xn = x + (size_t)n * C_CH * S_LEN;

    f32x4 acc[16];
    #pragma unroll
    for (int i = 0; i < 16; ++i) acc[i] = (f32x4){0.f, 0.f, 0.f, 0.f};

    #pragma unroll 1
    for (int cc = 0; cc < 8; ++cc) {
        short8 af;                                   // A[m=s][k=c]: lane m=sl, k=g*8+j
        #pragma unroll
        for (int j = 0; j < 8; ++j) {
            float v = xn[(size_t)(cc * 32 + g * 8 + j) * S_LEN + s0 + sl];
            af[j] = (short)f2bf(v);
        }
        #pragma unroll
        for (int t = 0; t < 16; ++t) {               // 0..7 theta tiles, 8..15 phi tiles
            const unsigned short* wp = wb + (size_t)(t >> 3) * (D_CH * C_CH)
                                          + (size_t)((t & 7) * 16 + sl) * C_CH + cc * 32 + g * 8;
            short8 bf = *reinterpret_cast<const short8*>(wp);
            acc[t] = __builtin_amdgcn_mfma_f32_16x16x32_bf16(af, bf, acc[t], 0, 0, 0);
        }
    }
    unsigned short* Qn = Qb + (size_t)n * S_LEN * D_CH;
    unsigned short* Kn = Kb + (size_t)n * S_LEN * D_CH;
    #pragma unroll
    for (int t = 0; t < 16; ++t) {
        const float bias = (t < 8 ? tb : pbias)[(t & 7) * 16 + sl];
        unsigned short* dst = (t < 8 ? Qn : Kn);
        #pragma unroll
        for (int r = 0; r < 4; ++r) {                // D row = g*4+r, col = sl
            dst[(size_t)(s0 + g * 4 + r) * D_CH + (t & 7) * 16 + sl] = f2bf(acc[t][r] + bias);
        }
    }
}

// ---------- kernel 4: flash attention, O^T = V^T * P^T ----------
// 512 blocks (2/CU), 4 waves, 32 q-rows/block. Wave w: s-group (w&1), i-half (w>>1);
// QK+softmax replicated within a pair, PV split. Counted-vmcnt double-buffered LDS.
__launch_bounds__(256, 2)
__global__ void nlm_attn_kernel(const unsigned short* __restrict__ Qb,
                                const unsigned short* __restrict__ Kb,
                                const unsigned short* __restrict__ xb,
                                float* __restrict__ out) {
    // XCD swizzle: 512 blocks, 64 consecutive work-items per XCD; 2 XCDs per batch n.
    const int sid  = blockIdx.x;
    const int newb = (sid & 7) * 64 + (sid >> 3);
    const int n    = newb >> 7;
    const int bx   = newb & 127;
    const int wave = threadIdx.x >> 6;
    const int lane = threadIdx.x & 63;
    const int sl   = lane & 15, g = lane >> 4;
    const int s0   = bx * 32 + (wave & 1) * 16;
    const int ih   = wave >> 1;                      // i-half: channels ih*128..ih*128+127

    __shared__ unsigned short Klds[2][32 * 128];     // [t-local][d], chunk-XOR swizzled
    __shared__ unsigned short Vlds[2][256 * 32];     // [c][t-local], chunk-XOR swizzled
    __shared__ unsigned short Plds[4][16 * 40];      // per-wave P^T staging, pitch 40

    const unsigned short* Qn = Qb + (size_t)n * S_LEN * D_CH;
    const unsigned short* Kn = Kb + (size_t)n * S_LEN * D_CH;
    const unsigned short* xn = xb + (size_t)n * C_CH * S_LEN;
    unsigned short* myP = &Plds[wave][0];

    short8 qf[4];                                    // B[k=d][n=s]: lane n=sl, k=g*8+j (+dc*32)
    #pragma unroll
    for (int dc = 0; dc < 4; ++dc)
        qf[dc] = *reinterpret_cast<const short8*>(Qn + (size_t)(s0 + sl) * D_CH + dc * 32 + g * 8);

    f32x4 oacc[8];                                   // O^T[i][s]: 128 i x 16 s per wave
    #pragma unroll
    for (int i = 0; i < 8; ++i) oacc[i] = (f32x4){0.f, 0.f, 0.f, 0.f};
    float m = -1e30f, lsum = 0.f;

    // ---- cooperative stage of tile `it` into buffer `buf` ----
    auto stage = [&](int it, int buf) {
        const int t0 = it * 32;
        // K tile: 32 rows x 256B; wave stages rows wave*8..wave*8+7 (2 insts).
        // LDS[r][q] = Global[t0+r][q ^ (r&7)]  (16B chunks q=0..15)
        #pragma unroll
        for (int i = 0; i < 2; ++i) {
            const int rl = wave * 8 + i * 4 + (lane >> 4);
            const int ch = (lane & 15) ^ (rl & 7);
            gload_lds16(Kn + (size_t)(t0 + rl) * D_CH + ch * 8,
                        &Klds[buf][(wave * 8 + i * 4) * 128]);
        }
        // V tile: 256 rows x 64B; wave stages rows wave*64..wave*64+63 (4 insts).
        // LDS[c][q] = Global[c][t0 + (q ^ ((c>>1)&3))*8]  (16B chunks q=0..3)
        #pragma unroll
        for (int i = 0; i < 4; ++i) {
            const int row = wave * 64 + i * 16 + (lane >> 2);
            const int ch = (lane & 3) ^ ((row >> 1) & 3);
            gload_lds16(xn + (size_t)row * S_LEN + t0 + ch * 8,
                        &Vlds[buf][(wave * 64 + i * 16) * 32]);
        }
    };

    stage(0, 0);
    stage(1, 1);

    #pragma unroll 1
    for (int it = 0; it < NT; ++it) {
        const int cur = it & 1;
        // tile `it` complete (6 loads/wave of tile it+1 may stay in flight)
        if (it + 1 < NT) { asm volatile("s_waitcnt vmcnt(6)" ::: "memory"); }
        else             { asm volatile("s_waitcnt vmcnt(0)" ::: "memory"); }
        __builtin_amdgcn_s_barrier();
        __builtin_amdgcn_sched_barrier(0);

        const unsigned short* Kl = &Klds[cur][0];
        const unsigned short* Vl = &Vlds[cur][0];

        f32x4 sacc0 = {0.f, 0.f, 0.f, 0.f}, sacc1 = {0.f, 0.f, 0.f, 0.f};
        __builtin_amdgcn_s_setprio(1);
        #pragma unroll
        for (int dc = 0; dc < 4; ++dc) {             // S^T = K_tile * Q^T (swapped operands)
            const int ch = (dc * 4 + g) ^ (sl & 7);  // un-swizzle
            short8 kf0 = *reinterpret_cast<const short8*>(Kl + sl * 128 + ch * 8);
            short8 kf1 = *reinterpret_cast<const short8*>(Kl + (16 + sl) * 128 + ch * 8);
            sacc0 = __builtin_amdgcn_mfma_f32_16x16x32_bf16(kf0, qf[dc], sacc0, 0, 0, 0);
            sacc1 = __builtin_amdgcn_mfma_f32_16x16x32_bf16(kf1, qf[dc], sacc1, 0, 0, 0);
        }
        __builtin_amdgcn_s_setprio(0);
        // lane holds S[s=sl][t = t0 + tt*16 + g*4 + r]
        float p[8];
        p[0] = sacc0[0]; p[1] = sacc0[1]; p[2] = sacc0[2]; p[3] = sacc0[3];
        p[4] = sacc1[0]; p[5] = sacc1[1]; p[6] = sacc1[2]; p[7] = sacc1[3];
        float pmax = fmaxf(fmaxf(fmaxf(p[0], p[1]), fmaxf(p[2], p[3])),
                           fmaxf(fmaxf(p[4], p[5]), fmaxf(p[6], p[7])));
        pmax = fmaxf(pmax, __shfl_xor(pmax, 16));
        pmax = fmaxf(pmax, __shfl_xor(pmax, 32));
        const float mnew = fmaxf(m, pmax);
        float rs = 0.f;
        #pragma unroll
        for (int j = 0; j < 8; ++j) {
            p[j] = __builtin_amdgcn_exp2f((p[j] - mnew) * LAMBDA);
            rs += p[j];
        }
        rs += __shfl_xor(rs, 16);
        rs += __shfl_xor(rs, 32);
        if (!__all(mnew == m)) {                     // wave-uniform skip-rescale
            const float alpha = __builtin_amdgcn_exp2f((m - mnew) * LAMBDA);
            lsum *= alpha;
            #pragma unroll
            for (int i = 0; i < 8; ++i) {
                oacc[i][0] *= alpha; oacc[i][1] *= alpha;
                oacc[i][2] *= alpha; oacc[i][3] *= alpha;
            }
            m = mnew;
        }
        lsum += rs;
        // P^T -> LDS (bf16), reload as B-fragment: lane n=sl needs P[sl][g*8+j]
        ushort4 w0, w1;
        w0.x = f2bf(p[0]); w0.y = f2bf(p[1]); w0.z = f2bf(p[2]); w0.w = f2bf(p[3]);
        w1.x = f2bf(p[4]); w1.y = f2bf(p[5]); w1.z = f2bf(p[6]); w1.w = f2bf(p[7]);
        *reinterpret_cast<ushort4*>(myP + sl * 40 + g * 4)      = w0;
        *reinterpret_cast<ushort4*>(myP + sl * 40 + 16 + g * 4) = w1;
        short8 pf = *reinterpret_cast<const short8*>(myP + sl * 40 + g * 8);
        // O^T += V^T * P^T : wave's i-half, 8 i-tiles
        __builtin_amdgcn_s_setprio(1);
        #pragma unroll
        for (int j = 0; j < 8; ++j) {
            const int c = (ih * 8 + j) * 16 + sl;
            const int ch = g ^ ((sl >> 1) & 3);      // un-swizzle ((c>>1)&3 == (sl>>1)&3)
            short8 vf = *reinterpret_cast<const short8*>(Vl + c * 32 + ch * 8);
            oacc[j] = __builtin_amdgcn_mfma_f32_16x16x32_bf16(vf, pf, oacc[j], 0, 0, 0);
        }
        __builtin_amdgcn_s_setprio(0);

        asm volatile("s_waitcnt lgkmcnt(0)" ::: "memory");
        __builtin_amdgcn_sched_barrier(0);
        __builtin_amdgcn_s_barrier();                // all waves done reading buf[cur]
        if (it + 2 < NT) stage(it + 2, cur);         // overwrite just-freed buffer
    }

    const float inv = 1.f / lsum;
    float* on = out + (size_t)n * C_CH * S_LEN;
    #pragma unroll
    for (int j = 0; j < 8; ++j) {
        #pragma unroll
        for (int r = 0; r < 4; ++r) {
            on[(size_t)((ih * 8 + j) * 16 + g * 4 + r) * S_LEN + s0 + sl] = oacc[j][r] * inv;
        }
    }
}

extern "C" void kernel_launch(void* const* d_in, const int* in_sizes, int n_in,
                              void* d_out, int out_size, void* d_ws, size_t ws_size,
                              hipStream_t stream) {
    const float* x  = (const float*)d_in[0];
    const float* tw = (const float*)d_in[1];
    const float* tb = (const float*)d_in[2];
    const float* pw = (const float*)d_in[3];
    const float* pb = (const float*)d_in[4];
    float* out = (float*)d_out;

    char* ws = (char*)d_ws;
    unsigned short* xb = (unsigned short*)(ws);               //  8,388,608 B
    unsigned short* Qb = (unsigned short*)(ws + 8388608);     //  4,194,304 B
    unsigned short* Kb = (unsigned short*)(ws + 12582912);    //  4,194,304 B
    unsigned short* wb = (unsigned short*)(ws + 16777216);    //    131,072 B

    nlm_conv_kernel<<<4096, 256, 0, stream>>>(x, xb);
    nlm_wconv_kernel<<<64, 256, 0, stream>>>(tw, pw, wb);
    nlm_proj_kernel<<<dim3(64, 4), 256, 0, stream>>>(x, wb, tb, pb, Qb, Kb);
    nlm_attn_kernel<<<512, 256, 0, stream>>>(Qb, Kb, xb, out);
}